// Round 1
// baseline (435.513 us; speedup 1.0000x reference)
//
#include <hip/hip_runtime.h>

#define NWIN 2048
#define NTOK 64
#define CDIM 256
#define NH 8
#define HD 32
#define QSCALE 0.17677669529663689f   // 32^-0.5

// LDS strides (bf16 units)
#define LDA 264   // x / attn_out region: 64 rows
#define LDQ 36    // q,k per head: 64 rows
#define LDV 72    // vT per head: 32 rows
#define LDP 68    // P per wave: 16 rows

typedef __bf16 bf16x4 __attribute__((ext_vector_type(4)));
typedef __bf16 bf16x8 __attribute__((ext_vector_type(8)));
typedef float  f32x4  __attribute__((ext_vector_type(4)));

__device__ __forceinline__ unsigned short f2bf(float f) {
    union { float f; unsigned u; } v; v.f = f;
    unsigned r = v.u + 0x7FFFu + ((v.u >> 16) & 1u);   // RNE
    return (unsigned short)(r >> 16);
}

// 16-B aligned load of 8 bf16
__device__ __forceinline__ bf16x8 ld16(const unsigned short* p) {
    return *(const bf16x8*)p;
}
// 8-B aligned load of 8 bf16 (two b64 reads)
__device__ __forceinline__ bf16x8 ld8u(const unsigned short* p) {
    bf16x4 lo = *(const bf16x4*)p;
    bf16x4 hi = *(const bf16x4*)(p + 4);
    return __builtin_shufflevector(lo, hi, 0, 1, 2, 3, 4, 5, 6, 7);
}

// ---- precast: weights fp32->bf16; bias_table -> relbT[h][col][row] fp32 ----
__global__ void precast_kernel(const float* __restrict__ wq, const float* __restrict__ wp,
                               const float* __restrict__ bt,
                               unsigned short* __restrict__ wqb, unsigned short* __restrict__ wpb,
                               float* __restrict__ relbT) {
    int i = blockIdx.x * 256 + threadIdx.x;
    if (i < 196608) {
        wqb[i] = f2bf(wq[i]);
    } else if (i < 262144) {
        wpb[i - 196608] = f2bf(wp[i - 196608]);
    } else if (i < 294912) {
        int j = i - 262144;            // h*4096 + c*64 + r  (c = key col, r = query row)
        int h = j >> 12;
        int c = (j >> 6) & 63;
        int r = j & 63;
        int yi = r >> 3, xi = r & 7, yj = c >> 3, xj = c & 7;
        int idx = (yi - yj + 7) * 15 + (xi - xj + 7);
        relbT[j] = bt[idx * NH + h];
    }
}

__global__ __launch_bounds__(512, 2)
void win_attn_kernel(const float* __restrict__ x, const float* __restrict__ mask,
                     const float* __restrict__ bq, const float* __restrict__ bp,
                     const unsigned short* __restrict__ wq, const unsigned short* __restrict__ wp,
                     const float* __restrict__ relbT, float* __restrict__ out) {
    // 161,792 B of LDS (<= 160 KiB)
    __shared__ __align__(16) unsigned short sm[80896];
    unsigned short* sA = sm;              // 64 x LDA   (x, then attn_out)
    unsigned short* sQ = sm + 16896;      // 8 x (64 x LDQ)
    unsigned short* sK = sm + 35328;      // 8 x (64 x LDQ)
    unsigned short* sV = sm + 53760;      // 8 x (32 x LDV)  (v transposed: [d][token])
    unsigned short* sP = sm + 72192;      // 8 x (16 x LDP)

    const int b    = blockIdx.x;
    const int tid  = threadIdx.x;
    const int wv   = tid >> 6;            // wave id == head id
    const int lane = tid & 63;
    const int lm   = lane & 15;
    const int quad = lane >> 4;
    const f32x4 fzero = {0.f, 0.f, 0.f, 0.f};

    // ---------- Phase 0: stage x window, fp32 -> bf16 ----------
    {
        const int row = tid >> 3;             // 64 rows, 8 threads/row
        const int c0  = (tid & 7) * 32;
        const float4* gx = (const float4*)(x + ((size_t)b * NTOK + row) * CDIM + c0);
        unsigned short* dst = sA + row * LDA + c0;
        #pragma unroll
        for (int i = 0; i < 8; ++i) {
            float4 v = gx[i];
            ushort4 u;
            u.x = f2bf(v.x); u.y = f2bf(v.y); u.z = f2bf(v.z); u.w = f2bf(v.w);
            *(ushort4*)(dst + i * 4) = u;
        }
    }
    __syncthreads();

    // ---------- Phase 1: qkv = x @ wq^T (+ bq); wave wv computes head wv ----------
    {
        const int h = wv;
        const int nbase[6] = { h*HD, h*HD + 16,
                               CDIM + h*HD, CDIM + h*HD + 16,
                               2*CDIM + h*HD, 2*CDIM + h*HD + 16 };
        f32x4 acc[4][6];
        #pragma unroll
        for (int mt = 0; mt < 4; ++mt)
            #pragma unroll
            for (int t = 0; t < 6; ++t) acc[mt][t] = fzero;

        #pragma unroll
        for (int ks = 0; ks < 8; ++ks) {
            bf16x8 bfr[6];
            #pragma unroll
            for (int t = 0; t < 6; ++t)
                bfr[t] = ld16(wq + (nbase[t] + lm) * CDIM + ks * 32 + quad * 8);
            bf16x8 afr[4];
            #pragma unroll
            for (int mt = 0; mt < 4; ++mt)
                afr[mt] = ld16(sA + (mt * 16 + lm) * LDA + ks * 32 + quad * 8);
            #pragma unroll
            for (int mt = 0; mt < 4; ++mt)
                #pragma unroll
                for (int t = 0; t < 6; ++t)
                    acc[mt][t] = __builtin_amdgcn_mfma_f32_16x16x32_bf16(afr[mt], bfr[t], acc[mt][t], 0, 0, 0);
        }

        float bqv[6];
        #pragma unroll
        for (int t = 0; t < 6; ++t) bqv[t] = bq[nbase[t] + lm];

        unsigned short* sQh = sQ + h * (NTOK * LDQ);
        unsigned short* sKh = sK + h * (NTOK * LDQ);
        unsigned short* sVh = sV + h * (HD * LDV);
        #pragma unroll
        for (int mt = 0; mt < 4; ++mt) {
            #pragma unroll
            for (int t = 0; t < 6; ++t) {
                #pragma unroll
                for (int reg = 0; reg < 4; ++reg) {
                    float val = acc[mt][t][reg] + bqv[t];
                    int tok = mt * 16 + quad * 4 + reg;
                    if (t < 2)      sQh[tok * LDQ + t * 16 + lm]          = f2bf(val * QSCALE);
                    else if (t < 4) sKh[tok * LDQ + (t - 2) * 16 + lm]    = f2bf(val);
                    else            sVh[((t - 4) * 16 + lm) * LDV + tok]  = f2bf(val);  // transposed
                }
            }
        }
    }
    __syncthreads();   // protects sA (x) reads vs. attn_out writes below

    // ---------- Phase 2: attention, one wave per head ----------
    {
        const int h = wv;
        const unsigned short* sQh = sQ + h * (NTOK * LDQ);
        const unsigned short* sKh = sK + h * (NTOK * LDQ);
        const unsigned short* sVh = sV + h * (HD * LDV);
        unsigned short* sPh = sP + wv * (16 * LDP);

        bf16x8 kf[4];                       // K B-frags, cached across chunks
        #pragma unroll
        for (int jt = 0; jt < 4; ++jt)
            kf[jt] = ld8u(sKh + (jt * 16 + lm) * LDQ + quad * 8);
        bf16x8 vf[2][2];                    // V B-frags
        #pragma unroll
        for (int nt = 0; nt < 2; ++nt)
            #pragma unroll
            for (int kk = 0; kk < 2; ++kk)
                vf[nt][kk] = ld16(sVh + (nt * 16 + lm) * LDV + kk * 32 + quad * 8);

        const float* maskb = mask + (size_t)b * (NTOK * NTOK);
        const float* relh  = relbT + h * (NTOK * NTOK);

        for (int rc = 0; rc < 4; ++rc) {
            const int m0 = rc * 16;
            bf16x8 qa = ld8u(sQh + (m0 + lm) * LDQ + quad * 8);
            f32x4 s[4];
            #pragma unroll
            for (int jt = 0; jt < 4; ++jt)
                s[jt] = __builtin_amdgcn_mfma_f32_16x16x32_bf16(qa, kf[jt], fzero, 0, 0, 0);

            // + rel_bias (+float4 via transposed table) + mask
            #pragma unroll
            for (int jt = 0; jt < 4; ++jt) {
                float4 rb4 = *(const float4*)(relh + (jt * 16 + lm) * 64 + m0 + quad * 4);
                float rbv[4] = { rb4.x, rb4.y, rb4.z, rb4.w };
                #pragma unroll
                for (int reg = 0; reg < 4; ++reg) {
                    int r = m0 + quad * 4 + reg;
                    s[jt][reg] += rbv[reg] + maskb[r * 64 + jt * 16 + lm];
                }
            }

            // softmax over cols; row r = m0 + quad*4 + reg lives in 16 lanes of group `quad`
            float mx[4], inv[4];
            #pragma unroll
            for (int reg = 0; reg < 4; ++reg) {
                float m_ = fmaxf(fmaxf(s[0][reg], s[1][reg]), fmaxf(s[2][reg], s[3][reg]));
                #pragma unroll
                for (int off = 1; off < 16; off <<= 1)
                    m_ = fmaxf(m_, __shfl_xor(m_, off, 64));
                mx[reg] = m_;
            }
            float p[4][4];
            #pragma unroll
            for (int jt = 0; jt < 4; ++jt)
                #pragma unroll
                for (int reg = 0; reg < 4; ++reg)
                    p[jt][reg] = __expf(s[jt][reg] - mx[reg]);
            #pragma unroll
            for (int reg = 0; reg < 4; ++reg) {
                float s_ = (p[0][reg] + p[1][reg]) + (p[2][reg] + p[3][reg]);
                #pragma unroll
                for (int off = 1; off < 16; off <<= 1)
                    s_ += __shfl_xor(s_, off, 64);
                inv[reg] = 1.0f / s_;    // defer row scaling to PV output
            }

            // P: C-layout -> LDS -> A-layout
            #pragma unroll
            for (int jt = 0; jt < 4; ++jt)
                #pragma unroll
                for (int reg = 0; reg < 4; ++reg)
                    sPh[(quad * 4 + reg) * LDP + jt * 16 + lm] = f2bf(p[jt][reg]);

            bf16x8 pa0 = ld8u(sPh + lm * LDP + quad * 8);
            bf16x8 pa1 = ld8u(sPh + lm * LDP + 32 + quad * 8);
            #pragma unroll
            for (int nt = 0; nt < 2; ++nt) {
                f32x4 o = __builtin_amdgcn_mfma_f32_16x16x32_bf16(pa0, vf[nt][0], fzero, 0, 0, 0);
                o = __builtin_amdgcn_mfma_f32_16x16x32_bf16(pa1, vf[nt][1], o, 0, 0, 0);
                #pragma unroll
                for (int reg = 0; reg < 4; ++reg) {
                    int r = m0 + quad * 4 + reg;
                    sA[r * LDA + h * HD + nt * 16 + lm] = f2bf(o[reg] * inv[reg]);
                }
            }
        }
    }
    __syncthreads();   // attn_out complete

    // ---------- Phase 3: out = attn_out @ wp^T + bp; wave wv does cols [wv*32, wv*32+32) ----------
    {
        const int n0 = wv * HD;
        f32x4 acc[4][2];
        #pragma unroll
        for (int mt = 0; mt < 4; ++mt) { acc[mt][0] = fzero; acc[mt][1] = fzero; }

        #pragma unroll
        for (int ks = 0; ks < 8; ++ks) {
            bf16x8 bfr[2];
            #pragma unroll
            for (int nt = 0; nt < 2; ++nt)
                bfr[nt] = ld16(wp + (n0 + nt * 16 + lm) * CDIM + ks * 32 + quad * 8);
            bf16x8 afr[4];
            #pragma unroll
            for (int mt = 0; mt < 4; ++mt)
                afr[mt] = ld16(sA + (mt * 16 + lm) * LDA + ks * 32 + quad * 8);
            #pragma unroll
            for (int mt = 0; mt < 4; ++mt)
                #pragma unroll
                for (int nt = 0; nt < 2; ++nt)
                    acc[mt][nt] = __builtin_amdgcn_mfma_f32_16x16x32_bf16(afr[mt], bfr[nt], acc[mt][nt], 0, 0, 0);
        }

        float bpv[2] = { bp[n0 + lm], bp[n0 + 16 + lm] };
        #pragma unroll
        for (int mt = 0; mt < 4; ++mt)
            #pragma unroll
            for (int nt = 0; nt < 2; ++nt)
                #pragma unroll
                for (int reg = 0; reg < 4; ++reg) {
                    int r = mt * 16 + quad * 4 + reg;
                    out[((size_t)b * NTOK + r) * CDIM + n0 + nt * 16 + lm] = acc[mt][nt][reg] + bpv[nt];
                }
    }
}

extern "C" void kernel_launch(void* const* d_in, const int* in_sizes, int n_in,
                              void* d_out, int out_size, void* d_ws, size_t ws_size,
                              hipStream_t stream) {
    const float* x    = (const float*)d_in[0];
    const float* mask = (const float*)d_in[1];
    const float* wq   = (const float*)d_in[2];
    const float* bq   = (const float*)d_in[3];
    const float* wp   = (const float*)d_in[4];
    const float* bp   = (const float*)d_in[5];
    const float* bt   = (const float*)d_in[6];

    unsigned short* wqb   = (unsigned short*)d_ws;              // 768x256 bf16
    unsigned short* wpb   = wqb + 196608;                        // 256x256 bf16
    float*          relbT = (float*)((char*)d_ws + 524288);     // 8x64x64 fp32 (h, col, row)
    float*          out   = (float*)d_out;

    precast_kernel<<<1152, 256, 0, stream>>>(wq, wp, bt, wqb, wpb, relbT);
    win_attn_kernel<<<NWIN, 512, 0, stream>>>(x, mask, bq, bp, wqb, wpb, relbT, out);
}